// Round 2
// baseline (272.064 us; speedup 1.0000x reference)
//
#include <hip/hip_runtime.h>
#include <hip/hip_bf16.h>

typedef __bf16 bf16;
typedef bf16 bf16x8 __attribute__((ext_vector_type(8)));
typedef bf16 bf16x4 __attribute__((ext_vector_type(4)));
typedef float f32x4 __attribute__((ext_vector_type(4)));

#define Bn 8
#define Cdim 256
#define Nn 2304
#define NH 4
#define DH 32
#define HID 128
// Q scale folded with log2(e) so softmax uses exp2 (native v_exp_f32)
#define QSCALE (0.17677669529663687f * 1.4426950408889634f)
// per-tensor ws size in bf16 elements: [32 bh][2304 n][32 d]
#define QSZ ((size_t)32 * Nn * DH)
#define WQ_ELEMS (3 * HID * Cdim)   // 98304
#define WO_ELEMS (Cdim * HID)       // 32768

// ---------------- Kernel 0: weight fp32 -> bf16 conversion -------------------
__global__ __launch_bounds__(256) void cvt_kernel(const float* __restrict__ wq,
                                                  const float* __restrict__ wo,
                                                  bf16* __restrict__ dst) {
    int i = blockIdx.x * 256 + threadIdx.x;
    if (i < WQ_ELEMS) dst[i] = (bf16)wq[i];
    if (i < WO_ELEMS) dst[WQ_ELEMS + i] = (bf16)wo[i];
}

// ---------------- Kernel 1: QKV projection -----------------------------------
// qkv[b,o,p] = sum_c w[o,c] x[b,c,p];  M=o(384), N=p, K=c(256)
// Output layout: Q/K/V [bh][n][d] bf16, Q pre-scaled.
__global__ __launch_bounds__(256) void qkv_kernel(const float* __restrict__ x,
                                                  const bf16* __restrict__ w,
                                                  bf16* __restrict__ ws) {
    // X^T tile: [p=64][c=256], row stride 264 elems (16B-aligned rows)
    __shared__ alignas(16) bf16 xt[64 * 264];
    const int p0  = blockIdx.x * 64;
    const int b   = blockIdx.y;
    const int tid = threadIdx.x;
    const float* xb = x + (size_t)b * Cdim * Nn;

    {   // stage + transpose + fp32->bf16: coalesced 64-wide fp32 reads per c-row
        const int pp = tid & 63;
        const int c0 = tid >> 6;
        #pragma unroll 4
        for (int k = 0; k < 64; ++k) {
            int c = c0 + 4 * k;
            xt[pp * 264 + c] = (bf16)xb[(size_t)c * Nn + p0 + pp];
        }
    }
    __syncthreads();

    const int lane = tid & 63;
    const int w4   = tid >> 6;
    const int l16  = lane & 15;
    const int quad = lane >> 4;

    // B-frags (X^T from LDS): lane holds x[c = kc*32+quad*8+j][p = l16]
    bf16x8 bx[8];
    #pragma unroll
    for (int kc = 0; kc < 8; ++kc)
        bx[kc] = *(const bf16x8*)&xt[(w4 * 16 + l16) * 264 + kc * 32 + quad * 8];

    const int p = p0 + w4 * 16 + l16;
    #pragma unroll 1
    for (int ot = 0; ot < 24; ++ot) {
        const int o0 = ot * 16;
        f32x4 acc = {0.f, 0.f, 0.f, 0.f};
        #pragma unroll
        for (int kc = 0; kc < 8; ++kc) {
            // A-frag: w[o = o0+l16][c = kc*32+quad*8 ..] contiguous 16B
            bf16x8 aw = *(const bf16x8*)&w[(size_t)(o0 + l16) * Cdim + kc * 32 + quad * 8];
            acc = __builtin_amdgcn_mfma_f32_16x16x32_bf16(aw, bx[kc], acc, 0, 0, 0);
        }
        // C layout: row(o_local)=quad*4+reg, col(p)=l16. 4 regs = 4 consecutive o
        // = 4 consecutive d within one (tensor, head): pack one 8B store.
        const int obase = o0 + quad * 4;
        const int t     = obase >> 7;     // 0=q 1=k 2=v
        const int rem   = obase & 127;
        const int h     = rem >> 5;
        const int dbase = rem & 31;
        const float sc  = (t == 0) ? QSCALE : 1.0f;
        bf16x4 v4;
        #pragma unroll
        for (int r = 0; r < 4; ++r) v4[r] = (bf16)(acc[r] * sc);
        size_t addr = (size_t)t * QSZ + ((size_t)(b * NH + h) * Nn + p) * DH + dbase;
        *(bf16x4*)&ws[addr] = v4;
    }
}

// ---------------- Kernel 2: flash attention ----------------------------------
// Per WG: one bh, 64 Q-rows (wave w owns rows i0+16w..+15, fully independent).
__global__ __launch_bounds__(256) void attn_kernel(bf16* __restrict__ ws) {
    __shared__ alignas(16) bf16 plds[4][16][64];   // per-wave P transpose buffer
    const int it  = blockIdx.x;
    const int bh  = blockIdx.y;
    const int tid = threadIdx.x;
    const int lane = tid & 63, w4 = tid >> 6, l16 = lane & 15, quad = lane >> 4;
    const int i0 = it * 64 + w4 * 16;

    const bf16* Qb = ws + (size_t)bh * Nn * DH;
    const bf16* Kb = Qb + QSZ;
    const bf16* Vb = Qb + 2 * QSZ;

    // A-frag of Q (reused all chunks): Q[i = i0+l16][d = quad*8 ..]
    const bf16x8 aq = *(const bf16x8*)&Qb[(size_t)(i0 + l16) * DH + quad * 8];

    f32x4 o0acc = {0.f,0.f,0.f,0.f}, o1acc = {0.f,0.f,0.f,0.f};
    float m[4] = {-INFINITY,-INFINITY,-INFINITY,-INFINITY};
    float l[4] = {0.f,0.f,0.f,0.f};

    for (int jc = 0; jc < 36; ++jc) {
        const int j0 = jc * 64;
        float s[4][4];
        #pragma unroll
        for (int jt = 0; jt < 4; ++jt) {
            // B-frag of K: K[j = j0+jt*16+l16][d = quad*8 ..] contiguous 16B
            bf16x8 bk = *(const bf16x8*)&Kb[(size_t)(j0 + jt * 16 + l16) * DH + quad * 8];
            f32x4 acc = {0.f,0.f,0.f,0.f};
            acc = __builtin_amdgcn_mfma_f32_16x16x32_bf16(aq, bk, acc, 0, 0, 0);
            #pragma unroll
            for (int r = 0; r < 4; ++r) s[jt][r] = acc[r];
        }
        // online softmax; state per row i_local = quad*4 + r, replicated in quad
        float alpha[4];
        #pragma unroll
        for (int r = 0; r < 4; ++r) {
            float mx = fmaxf(fmaxf(s[0][r], s[1][r]), fmaxf(s[2][r], s[3][r]));
            mx = fmaxf(mx, __shfl_xor(mx, 1));
            mx = fmaxf(mx, __shfl_xor(mx, 2));
            mx = fmaxf(mx, __shfl_xor(mx, 4));
            mx = fmaxf(mx, __shfl_xor(mx, 8));
            float mn = fmaxf(m[r], mx);
            alpha[r] = exp2f(m[r] - mn);
            m[r] = mn;
        }
        #pragma unroll
        for (int jt = 0; jt < 4; ++jt) {
            #pragma unroll
            for (int r = 0; r < 4; ++r) {
                float pv = exp2f(s[jt][r] - m[r]);
                s[jt][r] = pv;
                plds[w4][quad * 4 + r][jt * 16 + l16] = (bf16)pv;  // C->A transpose
            }
        }
        #pragma unroll
        for (int r = 0; r < 4; ++r) {
            float rs = s[0][r] + s[1][r] + s[2][r] + s[3][r];
            rs += __shfl_xor(rs, 1);
            rs += __shfl_xor(rs, 2);
            rs += __shfl_xor(rs, 4);
            rs += __shfl_xor(rs, 8);
            l[r] = l[r] * alpha[r] + rs;
            o0acc[r] *= alpha[r];
            o1acc[r] *= alpha[r];
        }
        // P in A layout: P[i = l16][j = kc*32 + quad*8 ..]
        const bf16x8 ap0 = *(const bf16x8*)&plds[w4][l16][quad * 8];
        const bf16x8 ap1 = *(const bf16x8*)&plds[w4][l16][32 + quad * 8];
        // V B-frags: B[k=j][n=d] = V[j][d] (layout matches; strided scalar loads)
        #pragma unroll
        for (int kc = 0; kc < 2; ++kc) {
            const bf16* vrow = Vb + (size_t)(j0 + kc * 32 + quad * 8) * DH + l16;
            bf16x8 bv;
            #pragma unroll
            for (int jj = 0; jj < 8; ++jj) bv[jj] = vrow[jj * DH];
            o0acc = __builtin_amdgcn_mfma_f32_16x16x32_bf16(kc ? ap1 : ap0, bv, o0acc, 0, 0, 0);
            #pragma unroll
            for (int jj = 0; jj < 8; ++jj) bv[jj] = vrow[jj * DH + 16];
            o1acc = __builtin_amdgcn_mfma_f32_16x16x32_bf16(kc ? ap1 : ap0, bv, o1acc, 0, 0, 0);
        }
    }
    bf16* Ab = ws + 3 * QSZ + (size_t)bh * Nn * DH;
    #pragma unroll
    for (int r = 0; r < 4; ++r) {
        float inv = 1.0f / l[r];
        Ab[(size_t)(i0 + quad * 4 + r) * DH + l16]      = (bf16)(o0acc[r] * inv);
        Ab[(size_t)(i0 + quad * 4 + r) * DH + 16 + l16] = (bf16)(o1acc[r] * inv);
    }
}

// ---------------- Kernel 3: output projection --------------------------------
// out[b,o,p] = b_out[o] + sum_c w_out[o,c] * A[b, c=h*32+d, p];  K-chunk == head
__global__ __launch_bounds__(256) void out_kernel(const bf16* __restrict__ wout,
                                                  const float* __restrict__ bout,
                                                  const bf16* __restrict__ Abuf,
                                                  float* __restrict__ out) {
    const int p0  = blockIdx.x * 64;
    const int b   = blockIdx.y;
    const int tid = threadIdx.x;
    const int lane = tid & 63, w4 = tid >> 6, l16 = lane & 15, quad = lane >> 4;
    const int p = p0 + w4 * 16 + l16;

    bf16x8 bfrag[4];
    #pragma unroll
    for (int h = 0; h < NH; ++h)
        bfrag[h] = *(const bf16x8*)&Abuf[((size_t)(b * NH + h) * Nn + p) * DH + quad * 8];

    #pragma unroll 1
    for (int ot = 0; ot < 16; ++ot) {
        const int o0 = ot * 16;
        f32x4 acc = {0.f,0.f,0.f,0.f};
        #pragma unroll
        for (int kc = 0; kc < 4; ++kc) {
            bf16x8 aw = *(const bf16x8*)&wout[(size_t)(o0 + l16) * HID + kc * 32 + quad * 8];
            acc = __builtin_amdgcn_mfma_f32_16x16x32_bf16(aw, bfrag[kc], acc, 0, 0, 0);
        }
        #pragma unroll
        for (int r = 0; r < 4; ++r) {
            const int o = o0 + quad * 4 + r;
            out[((size_t)b * Cdim + o) * Nn + p] = acc[r] + bout[o];
        }
    }
}

extern "C" void kernel_launch(void* const* d_in, const int* in_sizes, int n_in,
                              void* d_out, int out_size, void* d_ws, size_t ws_size,
                              hipStream_t stream) {
    const float* x     = (const float*)d_in[0];
    const float* w_qkv = (const float*)d_in[1];
    const float* w_out = (const float*)d_in[2];
    const float* b_out = (const float*)d_in[3];
    bf16* ws   = (bf16*)d_ws;         // 4*QSZ bf16 + converted weights = 19.1 MB
    float* out = (float*)d_out;

    bf16* wq_bf = ws + 4 * QSZ;
    bf16* wo_bf = wq_bf + WQ_ELEMS;

    cvt_kernel <<<dim3((WQ_ELEMS + 255) / 256), 256, 0, stream>>>(w_qkv, w_out, wq_bf);
    qkv_kernel <<<dim3(36,  Bn), 256, 0, stream>>>(x, wq_bf, ws);
    attn_kernel<<<dim3(36,  32), 256, 0, stream>>>(ws);
    out_kernel <<<dim3(36,  Bn), 256, 0, stream>>>(wo_bf, b_out, ws + 3 * QSZ, out);
}